// Round 9
// baseline (58.254 us; speedup 1.0000x reference)
//
#include <hip/hip_runtime.h>
#include <hip/hip_bf16.h>

// Taylor attention v9: q-split waves sharing double-buffered LDS K/V tiles
// staged via global_load_lds from FRAGMENT-LINEAR pre-packed workspace
// (tile = [Kfrag fp16 2KB | Vfrag bf16 4KB], granule g == lane g&63's 16B).
// 4 waves x 32q per block sweep the key range together (loads amortized 4x,
// ds_read->MFMA waited with fine lgkmcnt by the compiler; one vmcnt drain per
// tile at the barrier). fp16 QK^T, RNE-bf16 W/V PV, permlane32 W-transpose.
// 512 blocks; bid^1 complementary durations (72 tiles per pair), bid+256 equal.

typedef __attribute__((ext_vector_type(8))) short bf16x8;
typedef __attribute__((ext_vector_type(8))) _Float16 f16x8;
typedef __attribute__((ext_vector_type(4))) float f32x4;
typedef __attribute__((ext_vector_type(16))) float f32x16;
typedef unsigned int u32;
typedef unsigned short u16;

namespace {

constexpr int T_SEQ = 2048;
constexpr int DK    = 32;
constexpr int DV    = 64;
constexpr int NBH   = 32;

// w = ((C3*s + C2)*s + C1)*s + 1  with s = raw dot (1/sqrt(32) folded in)
constexpr float C1 = 0.17677669529663687f;   // c
constexpr float C2 = 0.015625f;              // c^2/2 (exact)
constexpr float C3 = 9.2071195e-4f;          // c^3/6

constexpr int    TILE_U16 = 3072;                           // 6 KB / tile
constexpr size_t WS_NEED  = (size_t)NBH * 64 * TILE_U16 * 2; // 12 MiB

__device__ __forceinline__ u32 pack_hi2(float f0, float f1) {
  return (__float_as_uint(f0) >> 16) | (__float_as_uint(f1) & 0xffff0000u);
}
__device__ __forceinline__ float trunc_bf(float f) {
  return __uint_as_float(__float_as_uint(f) & 0xffff0000u);
}
__device__ __forceinline__ u16 f2h(float f) {
  union { _Float16 h; u16 u; } c;
  c.h = (_Float16)f;             // RNE
  return c.u;
}
__device__ __forceinline__ u16 bfr(float f) {  // RNE bf16
  union { __hip_bfloat16 h; u16 u; } c;
  c.h = __hip_bfloat16(f);
  return c.u;
}
__device__ __forceinline__ u32 pack_rn2(float f0, float f1) {
  return (u32)bfr(f0) | ((u32)bfr(f1) << 16);
}
__device__ __forceinline__ void permswap(u32& a, u32& b) {
  asm volatile("v_permlane32_swap_b32 %0, %1" : "+v"(a), "+v"(b));
}
__device__ __forceinline__ void load16_lds(const u16* g, u16* lp) {
  __builtin_amdgcn_global_load_lds(
      (const __attribute__((address_space(1))) u32*)(const void*)g,
      (__attribute__((address_space(3))) u32*)(void*)lp, 16, 0, 0);
}

// -------- pack kernel: fragment-linear tiles [Kfrag fp16 | Vfrag bf16] -----
// granule g (0..383) of tile (bh,kt), 16B each, l=g&63, seg=g>>6:
//  seg t<2 : K[k0+(l&31)][t*16+(l>>5)*8+j]          (fp16)
//  seg 2+s : ct=s>>1,t=s&1: V[k0+t*16+(l>>5)*8+j][ct*32+(l&31)]  (bf16)
__global__ void pack_kv9(const float* __restrict__ Kg, const float* __restrict__ Vg,
                         u16* __restrict__ P) {
  const int bid = blockIdx.x;            // bh*64 + kt
  const int bh = bid >> 6, kt = bid & 63;
  const int k0 = kt * 32;
  u16* tile = P + (size_t)bid * TILE_U16;
  for (int g = threadIdx.x; g < 384; g += 256) {
    const int seg = g >> 6;
    const int l = g & 63, lo = l & 31, hi = l >> 5;
    ushort4 o0, o1;
    if (seg < 2) {
      const float* src = Kg + ((size_t)bh * T_SEQ + k0 + lo) * DK + seg * 16 + hi * 8;
      o0.x = f2h(src[0]); o0.y = f2h(src[1]); o0.z = f2h(src[2]); o0.w = f2h(src[3]);
      o1.x = f2h(src[4]); o1.y = f2h(src[5]); o1.z = f2h(src[6]); o1.w = f2h(src[7]);
    } else {
      const int ct = (seg - 2) >> 1, t = (seg - 2) & 1;
      const float* src = Vg + ((size_t)bh * T_SEQ + k0 + t * 16 + hi * 8) * DV
                         + ct * 32 + lo;
      o0.x = bfr(src[0 * DV]); o0.y = bfr(src[1 * DV]);
      o0.z = bfr(src[2 * DV]); o0.w = bfr(src[3 * DV]);
      o1.x = bfr(src[4 * DV]); o1.y = bfr(src[5 * DV]);
      o1.z = bfr(src[6 * DV]); o1.w = bfr(src[7 * DV]);
    }
    *(ushort4*)(tile + g * 8)     = o0;
    *(ushort4*)(tile + g * 8 + 4) = o1;
  }
}

// ---------------- main kernel (v9) ----------------

__global__ __launch_bounds__(256, 2)
void taylor_attn_v9(const float* __restrict__ Qg, const u16* __restrict__ P,
                    float* __restrict__ Outg) {
  __shared__ __align__(16) u16 KV[2][TILE_U16];   // 12.3 KB double buffer

  const int tid = threadIdx.x;
  const int l   = tid & 63;
  const int w   = tid >> 6;
  const int cq  = l & 31;
  const int hi  = l >> 5;

  // decode: bh = bid>>4; e = bid&15 -> a with bid^1 complementary (a <-> 15-a)
  const int bid  = blockIdx.x;
  const int bh   = bid >> 4;
  const int e    = bid & 15;
  const int core = (e >> 1) & 7;
  const int a    = (e & 1) ? (15 - core) : core;
  const int sw   = 4 * a + w;          // this wave's 32-row strip index
  const int q0w  = sw * 32;
  const int klast = 4 * a + 3;         // block sweeps tiles 0..klast

  const u16* tb = P + (size_t)bh * 64 * TILE_U16;

  // ---- Q B-fragments fp16 (once; col=q=cq, d = t*16 + hi*8 + j)
  f16x8 qf0, qf1;
  {
    const float* qp = Qg + ((size_t)bh * T_SEQ + q0w + cq) * DK + hi * 8;
    float4 a0 = *(const float4*)qp;
    float4 a1 = *(const float4*)(qp + 4);
    float4 b0 = *(const float4*)(qp + 16);
    float4 b1 = *(const float4*)(qp + 20);
    qf0[0] = (_Float16)a0.x; qf0[1] = (_Float16)a0.y;
    qf0[2] = (_Float16)a0.z; qf0[3] = (_Float16)a0.w;
    qf0[4] = (_Float16)a1.x; qf0[5] = (_Float16)a1.y;
    qf0[6] = (_Float16)a1.z; qf0[7] = (_Float16)a1.w;
    qf1[0] = (_Float16)b0.x; qf1[1] = (_Float16)b0.y;
    qf1[2] = (_Float16)b0.z; qf1[3] = (_Float16)b0.w;
    qf1[4] = (_Float16)b1.x; qf1[5] = (_Float16)b1.y;
    qf1[6] = (_Float16)b1.z; qf1[7] = (_Float16)b1.w;
  }

  f32x16 ZERO;
#pragma unroll
  for (int r = 0; r < 16; ++r) ZERO[r] = 0.f;
  f32x16 acc0 = ZERO, acc1 = ZERO;
  float zacc = 0.f;

  // wave w stages segment w (and w+4 for w<2): 6 x 1KB segments per tile
  auto STAGE = [&](int buf, int kt) {
    const u16* g = tb + (size_t)kt * TILE_U16;
    load16_lds(g + w * 512 + l * 8, &KV[buf][w * 512]);
    if (w < 2)
      load16_lds(g + (w + 4) * 512 + l * 8, &KV[buf][(w + 4) * 512]);
  };

  STAGE(0, 0);
  __syncthreads();   // vmcnt(0) drain + barrier: tile 0 ready
  int cur = 0;

#pragma unroll 1
  for (int kt = 0; kt <= klast; ++kt) {
    if (kt < klast) STAGE(cur ^ 1, kt + 1);   // issue next tile early

    if (kt <= sw) {
      const u16* B = &KV[cur][0];
      // K A-fragments (conflict-free ds_read_b128 at l*16)
      f16x8 kf0 = *(const f16x8*)(B + l * 8);
      f16x8 kf1 = *(const f16x8*)(B + 512 + l * 8);
      // swapped scores: D[col=q=cq][row k=(r&3)+8(r>>2)+4hi]
      f32x16 d = __builtin_amdgcn_mfma_f32_32x32x16_f16(kf0, qf0, ZERO, 0, 0, 0);
      d = __builtin_amdgcn_mfma_f32_32x32x16_f16(kf1, qf1, d, 0, 0, 0);

      float wv[16];
      const bool diag = (kt == sw);
#pragma unroll
      for (int r = 0; r < 16; ++r) {
        float sc = d[r];
        float t_ = __builtin_fmaf(sc, C3, C2);
        t_       = __builtin_fmaf(sc, t_, C1);
        float wr = __builtin_fmaf(sc, t_, 1.0f);
        if (diag) {
          const int krel = (r & 3) + 8 * (r >> 2) + 4 * hi;
          wr = (krel <= cq) ? wr : 0.f;
        }
        zacc += wr;
        wv[r] = wr;
      }

      // W -> RNE bf16, in-register transpose to PV A-frags
      union { bf16x8 v; u32 u[4]; } WH[2];
#pragma unroll
      for (int t = 0; t < 2; ++t) {
        const int b = t * 8;
        u32 p0 = pack_rn2(wv[b + 0], wv[b + 1]);
        u32 p1 = pack_rn2(wv[b + 2], wv[b + 3]);
        u32 p2 = pack_rn2(wv[b + 4], wv[b + 5]);
        u32 p3 = pack_rn2(wv[b + 6], wv[b + 7]);
        permswap(p0, p2); permswap(p1, p3);
        WH[t].u[0] = p0; WH[t].u[1] = p1; WH[t].u[2] = p2; WH[t].u[3] = p3;
      }

      // V B-fragments from LDS (conflict-free), PV: 4 MFMAs
      bf16x8 v00 = *(const bf16x8*)(B + 1024 + l * 8);
      bf16x8 v01 = *(const bf16x8*)(B + 1536 + l * 8);
      bf16x8 v10 = *(const bf16x8*)(B + 2048 + l * 8);
      bf16x8 v11 = *(const bf16x8*)(B + 2560 + l * 8);
      acc0 = __builtin_amdgcn_mfma_f32_32x32x16_bf16(WH[0].v, v00, acc0, 0, 0, 0);
      acc0 = __builtin_amdgcn_mfma_f32_32x32x16_bf16(WH[1].v, v01, acc0, 0, 0, 0);
      acc1 = __builtin_amdgcn_mfma_f32_32x32x16_bf16(WH[0].v, v10, acc1, 0, 0, 0);
      acc1 = __builtin_amdgcn_mfma_f32_32x32x16_bf16(WH[1].v, v11, acc1, 0, 0, 0);
    }

    __syncthreads();   // drains staged loads; orders buffer swap
    cur ^= 1;
  }

  // ---- Z: fold halves (lane l, l^32 share q=cq), transpose q->row via shfl
  float zt = zacc + __shfl_xor(zacc, 32);
  float iz = 1.0f / zt;                 // inv Z for q = cq (valid in all lanes)

  float* ob = Outg + ((size_t)bh * T_SEQ + q0w) * DV;
#pragma unroll
  for (int r = 0; r < 16; ++r) {
    const int qr = (r & 3) + 8 * (r >> 2) + 4 * hi;
    float izr = __shfl(iz, qr);         // z of row qr lives in lane qr
    ob[(size_t)qr * DV + cq]      = acc0[r] * izr;
    ob[(size_t)qr * DV + 32 + cq] = acc1[r] * izr;
  }
}

// ---------------- fallback (no workspace): v2 staged-LDS kernel ----------------

constexpr int QT_FB = 64;
constexpr int KT_FB = 32;
constexpr int LDSW  = 40;
constexpr float SCALE = 0.17677669529663687f;

__global__ __launch_bounds__(256, 4)
void taylor_attn_fb(const float* __restrict__ Qg, const float* __restrict__ Kg,
                    const float* __restrict__ Vg, float* __restrict__ Outg) {
  __shared__ __align__(16) unsigned short Qhi[QT_FB * LDSW], Qlo[QT_FB * LDSW];
  __shared__ __align__(16) unsigned short Khi_[KT_FB * LDSW], Klo_[KT_FB * LDSW];
  __shared__ __align__(16) unsigned short Vthi_[DV * LDSW], Vtlo_[DV * LDSW];
  __shared__ __align__(16) unsigned Wp[4][16 * 32];

  const int tid  = threadIdx.x;
  const int lane = tid & 63;
  const int wid  = tid >> 6;
  const int m    = lane & 15;
  const int g    = lane >> 4;

  const int bid = blockIdx.x;
  const int v   = bid >> 3;
  const int bh  = (bid & 7) * 4 + (v >> 5);
  const int qt  = 31 - (v & 31);
  const int q0  = qt * QT_FB;

  const float* Qbase = Qg + ((size_t)bh * T_SEQ + q0) * DK;
  const float* Kbase = Kg + (size_t)bh * T_SEQ * DK;
  const float* Vbase = Vg + (size_t)bh * T_SEQ * DV;

#pragma unroll
  for (int p = 0; p < 2; ++p) {
    int e = tid + p * 256, row = e >> 3, c4 = (e & 7) * 4;
    float4 f = *(const float4*)(Qbase + row * DK + c4);
    uint2 h, l;
    h.x = pack_hi2(f.x, f.y); h.y = pack_hi2(f.z, f.w);
    l.x = pack_hi2(f.x - trunc_bf(f.x), f.y - trunc_bf(f.y));
    l.y = pack_hi2(f.z - trunc_bf(f.z), f.w - trunc_bf(f.w));
    *(uint2*)&Qhi[row * LDSW + c4] = h;
    *(uint2*)&Qlo[row * LDSW + c4] = l;
  }
  __syncthreads();

  const int wq = wid * 16;
  const bf16x8 qhi = *(const bf16x8*)&Qhi[(wq + m) * LDSW + g * 8];
  const bf16x8 qlo = *(const bf16x8*)&Qlo[(wq + m) * LDSW + g * 8];

  f32x4 acc[4];
#pragma unroll
  for (int ct = 0; ct < 4; ++ct) acc[ct] = f32x4{0.f, 0.f, 0.f, 0.f};
  float zacc[4] = {0.f, 0.f, 0.f, 0.f};

  const int q_lane0 = q0 + wq + g * 4;
  const int q_wave_max = q0 + wq + 15;

  const int nkt = (q0 + QT_FB) / KT_FB;
  for (int kt = 0; kt < nkt; ++kt) {
    const int k0 = kt * KT_FB;
    __syncthreads();
    {
      int row = tid >> 3, c4 = (tid & 7) * 4;
      float4 f = *(const float4*)(Kbase + (size_t)(k0 + row) * DK + c4);
      uint2 h, l;
      h.x = pack_hi2(f.x, f.y); h.y = pack_hi2(f.z, f.w);
      l.x = pack_hi2(f.x - trunc_bf(f.x), f.y - trunc_bf(f.y));
      l.y = pack_hi2(f.z - trunc_bf(f.z), f.w - trunc_bf(f.w));
      *(uint2*)&Khi_[row * LDSW + c4] = h;
      *(uint2*)&Klo_[row * LDSW + c4] = l;
    }
    {
      int kk = (tid & 15) * 2, c4 = (tid >> 4) * 4;
      const float* vp = Vbase + (size_t)(k0 + kk) * DV + c4;
      float4 a = *(const float4*)vp;
      float4 b = *(const float4*)(vp + DV);
      float af[4] = {a.x, a.y, a.z, a.w};
      float bf_[4] = {b.x, b.y, b.z, b.w};
#pragma unroll
      for (int jj = 0; jj < 4; ++jj) {
        *(unsigned*)&Vthi_[(c4 + jj) * LDSW + kk] = pack_hi2(af[jj], bf_[jj]);
        *(unsigned*)&Vtlo_[(c4 + jj) * LDSW + kk] =
            pack_hi2(af[jj] - trunc_bf(af[jj]), bf_[jj] - trunc_bf(bf_[jj]));
      }
    }
    __syncthreads();

    if (k0 > q_wave_max) continue;

#pragma unroll
    for (int k16 = 0; k16 < 2; ++k16) {
      const int kcol0 = k16 * 16;
      bf16x8 khi = *(const bf16x8*)&Khi_[(kcol0 + m) * LDSW + g * 8];
      bf16x8 klo = *(const bf16x8*)&Klo_[(kcol0 + m) * LDSW + g * 8];
      f32x4 sc = {0.f, 0.f, 0.f, 0.f};
      sc = __builtin_amdgcn_mfma_f32_16x16x32_bf16(qhi, khi, sc, 0, 0, 0);
      sc = __builtin_amdgcn_mfma_f32_16x16x32_bf16(qhi, klo, sc, 0, 0, 0);
      sc = __builtin_amdgcn_mfma_f32_16x16x32_bf16(qlo, khi, sc, 0, 0, 0);
      const int k_abs = k0 + kcol0 + m;
      const int kcol  = kcol0 + m;
#pragma unroll
      for (int r = 0; r < 4; ++r) {
        float x  = sc[r] * SCALE;
        float a3 = __builtin_fmaf(x, 0.3333333333333333f, 1.0f);
        float a2 = __builtin_fmaf(x * 0.5f, a3, 1.0f);
        float wvv = __builtin_fmaf(x, a2, 1.0f);
        wvv = (k_abs <= q_lane0 + r) ? wvv : 0.0f;
        zacc[r] += wvv;
        float wl = wvv - trunc_bf(wvv);
        unsigned packed = (__float_as_uint(wvv) >> 16) |
                          (__float_as_uint(wl) & 0xffff0000u);
        const int q = g * 4 + r;
        Wp[wid][q * 32 + (((kcol >> 2) ^ (q & 7)) << 2) + (kcol & 3)] = packed;
      }
    }

    uint4 pa = *(const uint4*)&Wp[wid][m * 32 + (((2 * g) ^ (m & 7)) << 2)];
    uint4 pb = *(const uint4*)&Wp[wid][m * 32 + (((2 * g + 1) ^ (m & 7)) << 2)];
    union { bf16x8 v; unsigned u[4]; } WH, WL;
    WH.u[0] = (pa.x & 0xffffu) | (pa.y << 16);
    WH.u[1] = (pa.z & 0xffffu) | (pa.w << 16);
    WH.u[2] = (pb.x & 0xffffu) | (pb.y << 16);
    WH.u[3] = (pb.z & 0xffffu) | (pb.w << 16);
    WL.u[0] = (pa.x >> 16) | (pa.y & 0xffff0000u);
    WL.u[1] = (pa.z >> 16) | (pa.w & 0xffff0000u);
    WL.u[2] = (pb.x >> 16) | (pb.y & 0xffff0000u);
    WL.u[3] = (pb.z >> 16) | (pb.w & 0xffff0000u);

#pragma unroll
    for (int ct = 0; ct < 4; ++ct) {
      bf16x8 vhi = *(const bf16x8*)&Vthi_[(ct * 16 + m) * LDSW + g * 8];
      bf16x8 vlo = *(const bf16x8*)&Vtlo_[(ct * 16 + m) * LDSW + g * 8];
      acc[ct] = __builtin_amdgcn_mfma_f32_16x16x32_bf16(WH.v, vhi, acc[ct], 0, 0, 0);
      acc[ct] = __builtin_amdgcn_mfma_f32_16x16x32_bf16(WH.v, vlo, acc[ct], 0, 0, 0);
      acc[ct] = __builtin_amdgcn_mfma_f32_16x16x32_bf16(WL.v, vhi, acc[ct], 0, 0, 0);
    }
  }

  float invz[4];
#pragma unroll
  for (int r = 0; r < 4; ++r) {
    float z = zacc[r];
    z += __shfl_xor(z, 1); z += __shfl_xor(z, 2);
    z += __shfl_xor(z, 4); z += __shfl_xor(z, 8);
    invz[r] = 1.0f / z;
  }

  float* ob = Outg + ((size_t)bh * T_SEQ + (q0 + wq)) * DV;
#pragma unroll
  for (int ct = 0; ct < 4; ++ct)
#pragma unroll
    for (int r = 0; r < 4; ++r)
      ob[(g * 4 + r) * DV + ct * 16 + m] = acc[ct][r] * invz[r];
}

}  // namespace

extern "C" void kernel_launch(void* const* d_in, const int* in_sizes, int n_in,
                              void* d_out, int out_size, void* d_ws, size_t ws_size,
                              hipStream_t stream) {
  const float* Q = (const float*)d_in[0];
  const float* K = (const float*)d_in[1];
  const float* V = (const float*)d_in[2];
  float* Out = (float*)d_out;

  if (ws_size >= WS_NEED && d_ws != nullptr) {
    u16* P = (u16*)d_ws;
    hipLaunchKernelGGL(pack_kv9, dim3(2048), dim3(256), 0, stream, K, V, P);
    hipLaunchKernelGGL(taylor_attn_v9, dim3(512), dim3(256), 0, stream,
                       Q, P, Out);
  } else {
    hipLaunchKernelGGL(taylor_attn_fb, dim3(1024), dim3(256), 0, stream,
                       Q, K, V, Out);
  }
}

// Round 11
// 56.413 us; speedup vs baseline: 1.0326x; 1.0326x over previous
//
#include <hip/hip_runtime.h>
#include <hip/hip_bf16.h>

// Taylor attention v10b: v7's proven schedule (uniform 65-step strip-paired
// blocks, 4 waves stride-4 key interleave, diag peel, 4-slice LDS combine)
// with packed-fp16 math: cvt_pkrtz scores -> half2, v_pk_fma_f16 Horner poly,
// half2 regs double as PV A-frag pairs (permswap only), fp16 V, pk-tree Z.
// (v10 + fix: cvt_pkrtz returns __fp16x2, bridge via union.)

typedef __attribute__((ext_vector_type(8))) short bf16x8;
typedef __attribute__((ext_vector_type(8))) _Float16 f16x8;
typedef __attribute__((ext_vector_type(2))) _Float16 h2;
typedef __attribute__((ext_vector_type(2))) __fp16 fp16x2b;
typedef __attribute__((ext_vector_type(4))) float f32x4;
typedef __attribute__((ext_vector_type(16))) float f32x16;
typedef unsigned int u32;
typedef unsigned short u16;

namespace {

constexpr int T_SEQ = 2048;
constexpr int DK    = 32;
constexpr int DV    = 64;
constexpr int NBH   = 32;

// w = ((C3*s + C2)*s + C1)*s + 1  with s = raw dot (1/sqrt(32) folded in)
constexpr float C1 = 0.17677669529663687f;   // c
constexpr float C2 = 0.015625f;              // c^2/2 (exact)
constexpr float C3 = 9.2071195e-4f;          // c^3/6

// workspace layout (bytes): Khf (fp16) 4MiB | Vthf (fp16, transposed) 8MiB
constexpr size_t KHF_OFF  = 0;
constexpr size_t VTHF_OFF = (size_t)NBH * T_SEQ * DK * 2;             //  4 MiB
constexpr size_t WS_NEED  = VTHF_OFF + (size_t)NBH * DV * T_SEQ * 2;  // 12 MiB

__device__ __forceinline__ u32 pack_hi2(float f0, float f1) {
  return (__float_as_uint(f0) >> 16) | (__float_as_uint(f1) & 0xffff0000u);
}
__device__ __forceinline__ float trunc_bf(float f) {
  return __uint_as_float(__float_as_uint(f) & 0xffff0000u);
}
__device__ __forceinline__ u16 f2h(float f) {
  union { _Float16 h; u16 u; } c;
  c.h = (_Float16)f;             // RNE
  return c.u;
}
// Swap a.lanes[32:63] <-> b.lanes[0:31].
__device__ __forceinline__ void permswap(u32& a, u32& b) {
  asm volatile("v_permlane32_swap_b32 %0, %1" : "+v"(a), "+v"(b));
}

// ---------------- pack kernel (K -> fp16; V^T -> fp16) ----------------

__global__ void pack_kv(const float* __restrict__ Kg, const float* __restrict__ Vg,
                        u16* __restrict__ Khf, u16* __restrict__ Vthf) {
  __shared__ float tile[DV][33];
  const int bid = blockIdx.x;
  const int t   = threadIdx.x;
  if (bid < 2048) {  // ---- K: elementwise fp16 convert
    size_t i = ((size_t)bid * 256 + t) * 4;
    float4 f = *(const float4*)(Kg + i);
    ushort4 h;
    h.x = f2h(f.x); h.y = f2h(f.y); h.z = f2h(f.z); h.w = f2h(f.w);
    *(ushort4*)(Khf + i) = h;
  } else {           // ---- V: transpose 32k x 64c tiles, fp16
    const int vb = bid - 2048;
    const int bh = vb >> 6;
    const int k0 = (vb & 63) * 32;
    {
      const int kl = t >> 3, c0 = (t & 7) * 8;
      const float* src = Vg + ((size_t)bh * T_SEQ + k0 + kl) * DV + c0;
      float4 a = *(const float4*)src;
      float4 b = *(const float4*)(src + 4);
      tile[c0 + 0][kl] = a.x; tile[c0 + 1][kl] = a.y;
      tile[c0 + 2][kl] = a.z; tile[c0 + 3][kl] = a.w;
      tile[c0 + 4][kl] = b.x; tile[c0 + 5][kl] = b.y;
      tile[c0 + 6][kl] = b.z; tile[c0 + 7][kl] = b.w;
    }
    __syncthreads();
    {
      const int cl = t >> 2, k8 = (t & 3) * 8;
      ushort4 h0, h1;
      h0.x = f2h(tile[cl][k8 + 0]); h0.y = f2h(tile[cl][k8 + 1]);
      h0.z = f2h(tile[cl][k8 + 2]); h0.w = f2h(tile[cl][k8 + 3]);
      h1.x = f2h(tile[cl][k8 + 4]); h1.y = f2h(tile[cl][k8 + 5]);
      h1.z = f2h(tile[cl][k8 + 6]); h1.w = f2h(tile[cl][k8 + 7]);
      size_t off = ((size_t)(bh * DV + cl)) * T_SEQ + k0 + k8;
      *(ushort4*)(Vthf + off)     = h0;
      *(ushort4*)(Vthf + off + 4) = h1;
    }
  }
}

// ---------------- main kernel (v10) ----------------

__global__ __launch_bounds__(256, 4)
void taylor_attn_v10(const float* __restrict__ Qg, const u16* __restrict__ Khf,
                     const u16* __restrict__ Vthf, float* __restrict__ Outg) {
  __shared__ __align__(16) float Sp[4 * 2048];  // 4 wave partials, 32 KB
  __shared__ float Zp[4 * 32];

  const int tid = threadIdx.x;
  const int l   = tid & 63;
  const int w   = tid >> 6;
  const int cq  = l & 31;
  const int hi  = l >> 5;

  // decode: 8 XCDs x 4 bh x 32 strip-pairs; every block = exactly 65 steps.
  const int bid = blockIdx.x;
  const int xcd = bid & 7;
  const int r_  = bid >> 3;
  const int bh  = xcd * 4 + (r_ & 3);
  const int p   = r_ >> 2;

  const u16* kq = Khf + (size_t)bh * T_SEQ * DK + (size_t)cq * DK + hi * 8;
  const u16* vq = Vthf + (size_t)bh * DV * T_SEQ + (size_t)cq * T_SEQ + hi * 8;
  const float* qb = Qg + (size_t)bh * T_SEQ * DK;

  const h2 C3h = {(_Float16)C3, (_Float16)C3};
  const h2 C2h = {(_Float16)C2, (_Float16)C2};
  const h2 C1h = {(_Float16)C1, (_Float16)C1};
  const h2 ONEh = {(_Float16)1.0f, (_Float16)1.0f};

  f32x16 ZERO;
#pragma unroll
  for (int r = 0; r < 16; ++r) ZERO[r] = 0.f;

#pragma unroll 1
  for (int ph = 0; ph < 2; ++ph) {
    const int s  = ph ? (63 - p) : p;
    const int q0 = s * 32;

    if (ph) __syncthreads();  // combine reads of Sp done before reuse

    // ---- Q B-fragments, fp16 RNE
    f16x8 qf[2];
#pragma unroll
    for (int t = 0; t < 2; ++t) {
      const float* qp = qb + (size_t)(q0 + cq) * DK + t * 16 + hi * 8;
      float4 a = *(const float4*)qp;
      float4 b = *(const float4*)(qp + 4);
      f16x8 v;
      v[0] = (_Float16)a.x; v[1] = (_Float16)a.y;
      v[2] = (_Float16)a.z; v[3] = (_Float16)a.w;
      v[4] = (_Float16)b.x; v[5] = (_Float16)b.y;
      v[6] = (_Float16)b.z; v[7] = (_Float16)b.w;
      qf[t] = v;
    }

    f32x16 acc0 = ZERO, acc1 = ZERO;
    float zacc = 0.f;

    auto LOADK = [&](f16x8* kf, int kt) {
      const u16* kp = kq + (size_t)kt * 1024;
      kf[0] = *(const f16x8*)kp;
      kf[1] = *(const f16x8*)(kp + 16);
    };
    auto LOADV = [&](f16x8* vf, int kt) {
#pragma unroll
      for (int ct = 0; ct < 2; ++ct)
#pragma unroll
        for (int t = 0; t < 2; ++t)
          vf[ct * 2 + t] = *(const f16x8*)(
              vq + (size_t)ct * 32 * T_SEQ + kt * 32 + t * 16);
    };
    auto STEP = [&](const f16x8* kf, const f16x8* vf, bool diag) {
      f32x16 d = __builtin_amdgcn_mfma_f32_32x32x16_f16(kf[0], qf[0], ZERO, 0, 0, 0);
      d = __builtin_amdgcn_mfma_f32_32x32x16_f16(kf[1], qf[1], d, 0, 0, 0);

      // poly in packed fp16: wv[j] = pair for rows r=2j,2j+1
      union cvu { fp16x2b p; h2 h; u32 u; };
      cvu wv[8];
#pragma unroll
      for (int j = 0; j < 8; ++j) {
        cvu c;
        c.p = __builtin_amdgcn_cvt_pkrtz(d[2 * j], d[2 * j + 1]);
        h2 sc = c.h;
        h2 t_ = sc * C3h + C2h;
        t_    = sc * t_ + C1h;
        wv[j].h = sc * t_ + ONEh;
      }
      if (diag) {
#pragma unroll
        for (int j = 0; j < 8; ++j) {
          const int r0   = 2 * j;
          const int kre  = (r0 & 3) + 8 * (r0 >> 2) + 4 * hi;
          u32 msk = ((kre <= cq) ? 0xffffu : 0u) |
                    ((kre + 1 <= cq) ? 0xffff0000u : 0u);
          wv[j].u &= msk;
        }
      }
      // Z: pk tree then 2 cvt+adds
      {
        h2 zs = ((wv[0].h + wv[1].h) + (wv[2].h + wv[3].h)) +
                ((wv[4].h + wv[5].h) + (wv[6].h + wv[7].h));
        zacc += (float)zs[0] + (float)zs[1];
      }
      // in-register transpose: wv regs ARE the A-frag pairs; swap hi/lo halves
      union { f16x8 v; u32 u[4]; } WH[2];
#pragma unroll
      for (int t = 0; t < 2; ++t) {
        u32 p0 = wv[4 * t + 0].u, p1 = wv[4 * t + 1].u;
        u32 p2 = wv[4 * t + 2].u, p3 = wv[4 * t + 3].u;
        permswap(p0, p2); permswap(p1, p3);
        WH[t].u[0] = p0; WH[t].u[1] = p1; WH[t].u[2] = p2; WH[t].u[3] = p3;
      }
      acc0 = __builtin_amdgcn_mfma_f32_32x32x16_f16(WH[0].v, vf[0], acc0, 0, 0, 0);
      acc0 = __builtin_amdgcn_mfma_f32_32x32x16_f16(WH[1].v, vf[1], acc0, 0, 0, 0);
      acc1 = __builtin_amdgcn_mfma_f32_32x32x16_f16(WH[0].v, vf[2], acc1, 0, 0, 0);
      acc1 = __builtin_amdgcn_mfma_f32_32x32x16_f16(WH[1].v, vf[3], acc1, 0, 0, 0);
    };

    // ---- pipelined main loop (kt < s, mask-free): K double-buffered, V early
    {
      int kt = w;
      if (kt < s) {
        f16x8 kA[2], kB[2];
        LOADK(kA, kt);
        while (true) {
          int kn = kt + 4;
          if (kn < s) {
            LOADK(kB, kn);
            f16x8 vf[4]; LOADV(vf, kt);
            STEP(kA, vf, false);
            kt = kn;
          } else {
            f16x8 vf[4]; LOADV(vf, kt);
            STEP(kA, vf, false);
            break;
          }
          kn = kt + 4;
          if (kn < s) {
            LOADK(kA, kn);
            f16x8 vf[4]; LOADV(vf, kt);
            STEP(kB, vf, false);
            kt = kn;
          } else {
            f16x8 vf[4]; LOADV(vf, kt);
            STEP(kB, vf, false);
            break;
          }
        }
      }
    }
    // ---- peeled diagonal step (owner wave only, masked)
    if ((s & 3) == w) {
      f16x8 kD[2]; LOADK(kD, s);
      f16x8 vD[4]; LOADV(vD, s);
      STEP(kD, vD, true);
    }

    // ---- publish Z + S partials
    {
      float zt = zacc + __shfl_xor(zacc, 32);
      if (hi == 0) Zp[w * 32 + cq] = zt;
    }
#pragma unroll
    for (int r = 0; r < 16; ++r) {
      const int qr = (r & 3) + 8 * (r >> 2) + 4 * hi;
      Sp[w * 2048 + qr * 64 + cq]      = acc0[r];
      Sp[w * 2048 + qr * 64 + 32 + cq] = acc1[r];
    }
    __syncthreads();

    // ---- combine 4 slices + divide + store
    const f32x4* S4 = (const f32x4*)Sp;
#pragma unroll
    for (int i = 0; i < 2; ++i) {
      const int e4  = tid + i * 256;
      const int row = e4 >> 4;
      f32x4 ssum = S4[e4] + S4[512 + e4] + S4[1024 + e4] + S4[1536 + e4];
      float z = Zp[row] + Zp[32 + row] + Zp[64 + row] + Zp[96 + row];
      float inv = 1.0f / z;
      float4 o;
      o.x = ssum[0] * inv; o.y = ssum[1] * inv;
      o.z = ssum[2] * inv; o.w = ssum[3] * inv;
      *(float4*)(Outg + ((size_t)bh * T_SEQ + q0 + row) * DV + (e4 & 15) * 4) = o;
    }
  }
}

// ---------------- fallback (no workspace): v2 staged-LDS kernel ----------------

constexpr int QT_FB = 64;
constexpr int KT_FB = 32;
constexpr int LDSW  = 40;
constexpr float SCALE = 0.17677669529663687f;

__global__ __launch_bounds__(256, 4)
void taylor_attn_fb(const float* __restrict__ Qg, const float* __restrict__ Kg,
                    const float* __restrict__ Vg, float* __restrict__ Outg) {
  __shared__ __align__(16) unsigned short Qhi[QT_FB * LDSW], Qlo[QT_FB * LDSW];
  __shared__ __align__(16) unsigned short Khi_[KT_FB * LDSW], Klo_[KT_FB * LDSW];
  __shared__ __align__(16) unsigned short Vthi_[DV * LDSW], Vtlo_[DV * LDSW];
  __shared__ __align__(16) unsigned Wp[4][16 * 32];

  const int tid  = threadIdx.x;
  const int lane = tid & 63;
  const int wid  = tid >> 6;
  const int m    = lane & 15;
  const int g    = lane >> 4;

  const int bid = blockIdx.x;
  const int v   = bid >> 3;
  const int bh  = (bid & 7) * 4 + (v >> 5);
  const int qt  = 31 - (v & 31);
  const int q0  = qt * QT_FB;

  const float* Qbase = Qg + ((size_t)bh * T_SEQ + q0) * DK;
  const float* Kbase = Kg + (size_t)bh * T_SEQ * DK;
  const float* Vbase = Vg + (size_t)bh * T_SEQ * DV;

#pragma unroll
  for (int p = 0; p < 2; ++p) {
    int e = tid + p * 256, row = e >> 3, c4 = (e & 7) * 4;
    float4 f = *(const float4*)(Qbase + row * DK + c4);
    uint2 h, l;
    h.x = pack_hi2(f.x, f.y); h.y = pack_hi2(f.z, f.w);
    l.x = pack_hi2(f.x - trunc_bf(f.x), f.y - trunc_bf(f.y));
    l.y = pack_hi2(f.z - trunc_bf(f.z), f.w - trunc_bf(f.w));
    *(uint2*)&Qhi[row * LDSW + c4] = h;
    *(uint2*)&Qlo[row * LDSW + c4] = l;
  }
  __syncthreads();

  const int wq = wid * 16;
  const bf16x8 qhi = *(const bf16x8*)&Qhi[(wq + m) * LDSW + g * 8];
  const bf16x8 qlo = *(const bf16x8*)&Qlo[(wq + m) * LDSW + g * 8];

  f32x4 acc[4];
#pragma unroll
  for (int ct = 0; ct < 4; ++ct) acc[ct] = f32x4{0.f, 0.f, 0.f, 0.f};
  float zacc[4] = {0.f, 0.f, 0.f, 0.f};

  const int q_lane0 = q0 + wq + g * 4;
  const int q_wave_max = q0 + wq + 15;

  const int nkt = (q0 + QT_FB) / KT_FB;
  for (int kt = 0; kt < nkt; ++kt) {
    const int k0 = kt * KT_FB;
    __syncthreads();
    {
      int row = tid >> 3, c4 = (tid & 7) * 4;
      float4 f = *(const float4*)(Kbase + (size_t)(k0 + row) * DK + c4);
      uint2 h, l;
      h.x = pack_hi2(f.x, f.y); h.y = pack_hi2(f.z, f.w);
      l.x = pack_hi2(f.x - trunc_bf(f.x), f.y - trunc_bf(f.y));
      l.y = pack_hi2(f.z - trunc_bf(f.z), f.w - trunc_bf(f.w));
      *(uint2*)&Khi_[row * LDSW + c4] = h;
      *(uint2*)&Klo_[row * LDSW + c4] = l;
    }
    {
      int kk = (tid & 15) * 2, c4 = (tid >> 4) * 4;
      const float* vp = Vbase + (size_t)(k0 + kk) * DV + c4;
      float4 a = *(const float4*)vp;
      float4 b = *(const float4*)(vp + DV);
      float af[4] = {a.x, a.y, a.z, a.w};
      float bf_[4] = {b.x, b.y, b.z, b.w};
#pragma unroll
      for (int jj = 0; jj < 4; ++jj) {
        *(unsigned*)&Vthi_[(c4 + jj) * LDSW + kk] = pack_hi2(af[jj], bf_[jj]);
        *(unsigned*)&Vtlo_[(c4 + jj) * LDSW + kk] =
            pack_hi2(af[jj] - trunc_bf(af[jj]), bf_[jj] - trunc_bf(bf_[jj]));
      }
    }
    __syncthreads();

    if (k0 > q_wave_max) continue;

#pragma unroll
    for (int k16 = 0; k16 < 2; ++k16) {
      const int kcol0 = k16 * 16;
      bf16x8 khi = *(const bf16x8*)&Khi_[(kcol0 + m) * LDSW + g * 8];
      bf16x8 klo = *(const bf16x8*)&Klo_[(kcol0 + m) * LDSW + g * 8];
      f32x4 sc = {0.f, 0.f, 0.f, 0.f};
      sc = __builtin_amdgcn_mfma_f32_16x16x32_bf16(qhi, khi, sc, 0, 0, 0);
      sc = __builtin_amdgcn_mfma_f32_16x16x32_bf16(qhi, klo, sc, 0, 0, 0);
      sc = __builtin_amdgcn_mfma_f32_16x16x32_bf16(qlo, khi, sc, 0, 0, 0);
      const int k_abs = k0 + kcol0 + m;
      const int kcol  = kcol0 + m;
#pragma unroll
      for (int r = 0; r < 4; ++r) {
        float x  = sc[r] * SCALE;
        float a3 = __builtin_fmaf(x, 0.3333333333333333f, 1.0f);
        float a2 = __builtin_fmaf(x * 0.5f, a3, 1.0f);
        float wvv = __builtin_fmaf(x, a2, 1.0f);
        wvv = (k_abs <= q_lane0 + r) ? wvv : 0.0f;
        zacc[r] += wvv;
        float wl = wvv - trunc_bf(wvv);
        unsigned packed = (__float_as_uint(wvv) >> 16) |
                          (__float_as_uint(wl) & 0xffff0000u);
        const int q = g * 4 + r;
        Wp[wid][q * 32 + (((kcol >> 2) ^ (q & 7)) << 2) + (kcol & 3)] = packed;
      }
    }

    uint4 pa = *(const uint4*)&Wp[wid][m * 32 + (((2 * g) ^ (m & 7)) << 2)];
    uint4 pb = *(const uint4*)&Wp[wid][m * 32 + (((2 * g + 1) ^ (m & 7)) << 2)];
    union { bf16x8 v; unsigned u[4]; } WH, WL;
    WH.u[0] = (pa.x & 0xffffu) | (pa.y << 16);
    WH.u[1] = (pa.z & 0xffffu) | (pa.w << 16);
    WH.u[2] = (pb.x & 0xffffu) | (pb.y << 16);
    WH.u[3] = (pb.z & 0xffffu) | (pb.w << 16);
    WL.u[0] = (pa.x >> 16) | (pa.y & 0xffff0000u);
    WL.u[1] = (pa.z >> 16) | (pa.w & 0xffff0000u);
    WL.u[2] = (pb.x >> 16) | (pb.y & 0xffff0000u);
    WL.u[3] = (pb.z >> 16) | (pb.w & 0xffff0000u);

#pragma unroll
    for (int ct = 0; ct < 4; ++ct) {
      bf16x8 vhi = *(const bf16x8*)&Vthi_[(ct * 16 + m) * LDSW + g * 8];
      bf16x8 vlo = *(const bf16x8*)&Vtlo_[(ct * 16 + m) * LDSW + g * 8];
      acc[ct] = __builtin_amdgcn_mfma_f32_16x16x32_bf16(WH.v, vhi, acc[ct], 0, 0, 0);
      acc[ct] = __builtin_amdgcn_mfma_f32_16x16x32_bf16(WH.v, vlo, acc[ct], 0, 0, 0);
      acc[ct] = __builtin_amdgcn_mfma_f32_16x16x32_bf16(WL.v, vhi, acc[ct], 0, 0, 0);
    }
  }

  float invz[4];
#pragma unroll
  for (int r = 0; r < 4; ++r) {
    float z = zacc[r];
    z += __shfl_xor(z, 1); z += __shfl_xor(z, 2);
    z += __shfl_xor(z, 4); z += __shfl_xor(z, 8);
    invz[r] = 1.0f / z;
  }

  float* ob = Outg + ((size_t)bh * T_SEQ + (q0 + wq)) * DV;
#pragma unroll
  for (int ct = 0; ct < 4; ++ct)
#pragma unroll
    for (int r = 0; r < 4; ++r)
      ob[(g * 4 + r) * DV + ct * 16 + m] = acc[ct][r] * invz[r];
}

}  // namespace

extern "C" void kernel_launch(void* const* d_in, const int* in_sizes, int n_in,
                              void* d_out, int out_size, void* d_ws, size_t ws_size,
                              hipStream_t stream) {
  const float* Q = (const float*)d_in[0];
  const float* K = (const float*)d_in[1];
  const float* V = (const float*)d_in[2];
  float* Out = (float*)d_out;

  if (ws_size >= WS_NEED && d_ws != nullptr) {
    u16* khf  = (u16*)((char*)d_ws + KHF_OFF);
    u16* vthf = (u16*)((char*)d_ws + VTHF_OFF);

    hipLaunchKernelGGL(pack_kv, dim3(4096), dim3(256), 0, stream, K, V, khf, vthf);
    hipLaunchKernelGGL(taylor_attn_v10, dim3(1024), dim3(256), 0, stream,
                       Q, khf, vthf, Out);
  } else {
    hipLaunchKernelGGL(taylor_attn_fb, dim3(1024), dim3(256), 0, stream,
                       Q, K, V, Out);
  }
}